// Round 6
// baseline (290.172 us; speedup 1.0000x reference)
//
#include <hip/hip_runtime.h>

// Problem constants (fixed by the reference file).
static constexpr int B = 16;
static constexpr int N = 250000;   // 15625 * 16
static constexpr int F = 500000;
static constexpr int C3 = 3 * F;   // corners = 1,500,000
static constexpr int E = 6 * F;    // directed edges = 3,000,000 (even per vertex)
static constexpr int RW = 48;      // ushorts per vt row: 3 comps * 16 batches (96 B)

// ---- workspace layout (bytes) ----
static constexpr size_t OFF_VT  = 0;                                        // ushort[N][48] = 24 MB
static constexpr size_t OFF_ADJ = (size_t)N * RW * 2;                       // int[E] = 12 MB
static constexpr size_t OFF_DEG = OFF_ADJ + (size_t)E * sizeof(int);        // uint[N]
static constexpr size_t OFF_CNT = OFF_DEG + (size_t)N * sizeof(unsigned);   // uint (padded 256)
static constexpr size_t OFF_STA = OFF_CNT + 256;                            // uint[N]
static constexpr size_t OFF_RNK = OFF_STA + (size_t)N * sizeof(unsigned);   // uint[3F] = 6 MB
static constexpr size_t WS_NEED = OFF_RNK + (size_t)C3 * sizeof(unsigned);  // ~44 MB (< proven 63 MB)

__device__ __forceinline__ unsigned short f2bf(float f) {
    unsigned u = __float_as_uint(f);
    return (unsigned short)((u + 0x7FFFu + ((u >> 16) & 1u)) >> 16);  // RNE
}

// Fused: (B,N,3) fp32 -> (N,3,16) bf16 transpose  +  corner ranking.
__global__ __launch_bounds__(256) void uls_setup(
    const float* __restrict__ vert, const int* __restrict__ faces,
    unsigned short* __restrict__ vt, unsigned* __restrict__ deg,
    unsigned* __restrict__ rank)
{
    __shared__ unsigned short lus[16 * RW];   // 768 ushorts
    int t = threadIdx.x;
    int n0 = blockIdx.x * 16;
    int b = t >> 4, v = t & 15;

    // rank part first: the long-latency atomic hides behind the transpose.
    int e = blockIdx.x * 256 + t;             // 4M threads cover C3=1.5M corners
    unsigned rv = 0;
    bool e_ok = (e < C3);
    int dst = e_ok ? faces[e] : 0;            // coalesced 4 B
    if (e_ok) rv = atomicAdd(&deg[dst], 2u);  // the only atomic in the pipeline

    const float* s = vert + (size_t)b * (N * 3) + (size_t)(n0 + v) * 3;
    lus[v * RW + 0 * 16 + b] = f2bf(s[0]);
    lus[v * RW + 1 * 16 + b] = f2bf(s[1]);
    lus[v * RW + 2 * 16 + b] = f2bf(s[2]);
    __syncthreads();
    // 768 ushorts = 192 uint2; threads 0..191 write 8 B each (coalesced)
    const uint2* lu2 = (const uint2*)lus;
    uint2* d2 = (uint2*)(vt + (size_t)n0 * RW);
    if (t < 192) d2[t] = lu2[t];

    if (e_ok) rank[e] = rv;                   // coalesced 4 B store
}

// start[n] = block-local exclusive scan + atomically allocated block base.
__global__ __launch_bounds__(256) void uls_alloc(
    const unsigned* __restrict__ deg, unsigned* __restrict__ start,
    unsigned* __restrict__ counter)
{
    __shared__ unsigned s[256];
    __shared__ unsigned base;
    int t = threadIdx.x;
    int n = blockIdx.x * 256 + t;
    unsigned d = (n < N) ? deg[n] : 0u;
    s[t] = d;
    __syncthreads();
    for (int off = 1; off < 256; off <<= 1) {
        unsigned v = (t >= off) ? s[t - off] : 0u;
        __syncthreads();
        s[t] += v;
        __syncthreads();
    }
    if (t == 255) base = atomicAdd(counter, s[255]);
    __syncthreads();
    if (n < N) start[n] = base + (s[t] - d);
}

// Atomic-free placement: slot = start[dst] + rank[e].
// The scattered 8 B store is NONTEMPORAL: adj lines receive ~7.6 stores from
// random XCDs; with normal write-back L2 each store ping-pongs line ownership
// and flushes a full 64 B line (R3: WRITE=97 MB for 12 MB payload). nt stores
// bypass the per-XCD L2 so partial writes merge in the shared level instead.
__global__ __launch_bounds__(256) void uls_fill(
    const int* __restrict__ faces, const unsigned* __restrict__ start,
    const unsigned* __restrict__ rank, long long* __restrict__ adj)
{
    int e = blockIdx.x * 256 + threadIdx.x;
    if (e >= C3) return;
    int f = e / 3;
    int c = e - 3 * f;
    int a  = faces[3 * f + 0];
    int b  = faces[3 * f + 1];
    int cc = faces[3 * f + 2];
    int dst = (c == 0) ? a : (c == 1) ? b : cc;
    int p0  = (c == 0) ? b : a;
    int p1  = (c == 2) ? b : cc;
    unsigned p = start[dst] + rank[e];            // both even -> 8 B aligned
    long long pair = (unsigned long long)(unsigned)p0 |
                     ((unsigned long long)(unsigned)p1 << 32);
    __builtin_nontemporal_store(pair, adj + (p >> 1));
}

// 4 lanes per vertex; lane q owns batches 4q..4q+3 via uint2 (8 B) loads.
__device__ __forceinline__ void acc_row(const unsigned short* __restrict__ r,
                                        int q, float (&acc)[3][4]) {
#pragma unroll
    for (int c = 0; c < 3; ++c) {
        uint2 u = *(const uint2*)(r + c * 16 + 4 * q);  // 8 B aligned
        acc[c][0] += __uint_as_float(u.x << 16);
        acc[c][1] += __uint_as_float(u.x & 0xFFFF0000u);
        acc[c][2] += __uint_as_float(u.y << 16);
        acc[c][3] += __uint_as_float(u.y & 0xFFFF0000u);
    }
}

__device__ __forceinline__ int2 nt_load_pair(const int* p) {
    long long v = __builtin_nontemporal_load((const long long*)p);
    return make_int2((int)(unsigned)(v & 0xFFFFFFFFull), (int)(unsigned)(v >> 32));
}

__global__ __launch_bounds__(256) void uls_gather(
    const unsigned short* __restrict__ vt, const int* __restrict__ adj,
    const unsigned* __restrict__ start, const unsigned* __restrict__ deg,
    float* __restrict__ out)
{
    __shared__ float lds[16 * 65];           // [batch][vert], stride 65
    int t = threadIdx.x;
    int q = t & 3;                           // batch quarter
    int v = t >> 2;                          // vertex within block (0..63)
    int n = blockIdx.x * 64 + v;
    bool n_ok = (n < N);

    unsigned d  = n_ok ? deg[n]   : 0u;      // uniform per 4-lane group
    unsigned s0 = n_ok ? start[n] : 0u;

    float acc[3][4] = {{0.f,0.f,0.f,0.f},{0.f,0.f,0.f,0.f},{0.f,0.f,0.f,0.f}};
    unsigned j = 0;
    for (; j + 4 <= d; j += 4) {             // 4 rows x 3 comps = 12 loads in flight
        int2 p0 = nt_load_pair(adj + s0 + j);      // adj read-once: keep out of L2
        int2 p1 = nt_load_pair(adj + s0 + j + 2);
        acc_row(vt + (size_t)p0.x * RW, q, acc);
        acc_row(vt + (size_t)p0.y * RW, q, acc);
        acc_row(vt + (size_t)p1.x * RW, q, acc);
        acc_row(vt + (size_t)p1.y * RW, q, acc);
    }
    if (j < d) {                             // deg even: remainder exactly 0 or 2
        int2 p0 = nt_load_pair(adj + s0 + j);
        acc_row(vt + (size_t)p0.x * RW, q, acc);
        acc_row(vt + (size_t)p0.y * RW, q, acc);
    }

    if (n_ok) {
        float self[3][4];
        const unsigned short* rs = vt + (size_t)n * RW;
#pragma unroll
        for (int c = 0; c < 3; ++c) {
            uint2 u = *(const uint2*)(rs + c * 16 + 4 * q);
            self[c][0] = __uint_as_float(u.x << 16);
            self[c][1] = __uint_as_float(u.x & 0xFFFF0000u);
            self[c][2] = __uint_as_float(u.y << 16);
            self[c][3] = __uint_as_float(u.y & 0xFFFF0000u);
        }
        float inv = 1.0f / fmaxf((float)d, 1.0f);
#pragma unroll
        for (int k = 0; k < 4; ++k) {
            float lx = acc[0][k] * inv - self[0][k];
            float ly = acc[1][k] * inv - self[1][k];
            float lz = acc[2][k] * inv - self[2][k];
            lds[(4 * q + k) * 65 + v] = sqrtf(lx * lx + ly * ly + lz * lz);
        }
    }
    __syncthreads();
    // coalesced nontemporal output (never re-read; don't evict vt from L2)
    int vo = t & 63;
    int nn = blockIdx.x * 64 + vo;
    if (nn < N) {
#pragma unroll
        for (int k = 0; k < 4; ++k) {
            int bo = (t >> 6) + 4 * k;
            __builtin_nontemporal_store(lds[bo * 65 + vo], out + (size_t)bo * N + nn);
        }
    }
}

extern "C" void kernel_launch(void* const* d_in, const int* in_sizes, int n_in,
                              void* d_out, int out_size, void* d_ws, size_t ws_size,
                              hipStream_t stream) {
    const float* vert  = (const float*)d_in[0];   // (B, N, 3) fp32
    const int*   faces = (const int*)d_in[1];     // (F, 3) int32
    float* out = (float*)d_out;                   // (B, N) fp32
    char* ws = (char*)d_ws;
    (void)ws_size;  // WS_NEED ~44 MB; harness proven >= 63 MB in round 2

    unsigned short* vt      = (unsigned short*)(ws + OFF_VT);
    int*            adj     = (int*)(ws + OFF_ADJ);
    unsigned*       deg     = (unsigned*)(ws + OFF_DEG);
    unsigned*       counter = (unsigned*)(ws + OFF_CNT);
    unsigned*       start   = (unsigned*)(ws + OFF_STA);
    unsigned*       rank    = (unsigned*)(ws + OFF_RNK);

    // zero deg + counter (start/rank/adj fully overwritten downstream)
    hipMemsetAsync(ws + OFF_DEG, 0, (OFF_CNT + 256) - OFF_DEG, stream);

    uls_setup<<<N / 16, 256, 0, stream>>>(vert, faces, vt, deg, rank);
    uls_alloc<<<(N + 255) / 256, 256, 0, stream>>>(deg, start, counter);
    uls_fill<<<(C3 + 255) / 256, 256, 0, stream>>>(faces, start, rank, (long long*)adj);
    uls_gather<<<(N + 63) / 64, 256, 0, stream>>>(vt, adj, start, deg, out);
}

// Round 7
// 265.808 us; speedup vs baseline: 1.0917x; 1.0917x over previous
//
#include <hip/hip_runtime.h>

// Problem constants (fixed by the reference file).
static constexpr int B = 16;
static constexpr int N = 250000;   // 15625 * 16
static constexpr int F = 500000;
static constexpr int C3 = 3 * F;   // corners = 1,500,000
static constexpr int E = 6 * F;    // directed edges (CSR fallback)
static constexpr int RW = 48;      // ushorts per vt row: 3 comps * 16 batches (96 B)

// ---- DIRECT layout (bytes): vt | deg | adjp[N][CAP] (int2 pairs) ----
static constexpr size_t D_VT  = 0;                                   // 24,000,000
static constexpr size_t D_DEG = (size_t)N * RW * 2;                  // 24,000,000
static constexpr size_t D_ADJ = D_DEG + (size_t)N * sizeof(unsigned);// 25,000,000 (8B-aligned)
static constexpr size_t ws_direct(int cap) { return D_ADJ + (size_t)N * cap * 8; }
// cap=32 -> 89,000,000 ; cap=28 -> 81,000,000

// ---- CSR fallback layout (proven to fit: 63 MB was available in R2) ----
static constexpr size_t C_VT  = 0;
static constexpr size_t C_ADJ = (size_t)N * RW * 2;                      // 24,000,000
static constexpr size_t C_DEG = C_ADJ + (size_t)E * sizeof(int);         // 36,000,000
static constexpr size_t C_CNT = C_DEG + (size_t)N * sizeof(unsigned);    // 37,000,000
static constexpr size_t C_STA = C_CNT + 256;
static constexpr size_t C_RNK = C_STA + (size_t)N * sizeof(unsigned);
static constexpr size_t C_NEED = C_RNK + (size_t)C3 * sizeof(unsigned);  // ~44 MB

__device__ __forceinline__ unsigned short f2bf(float f) {
    unsigned u = __float_as_uint(f);
    return (unsigned short)((u + 0x7FFFu + ((u >> 16) & 1u)) >> 16);  // RNE
}

// ================= DIRECT path =================

// Fused: transpose (B,N,3)fp32 -> (N,3,16)bf16  +  corner rank  +  adj write.
// atomicAdd on deg IS the slot allocator: pair index = old_deg/2.
template <int CAP>
__global__ __launch_bounds__(256) void uls_setup_direct(
    const float* __restrict__ vert, const int* __restrict__ faces,
    unsigned short* __restrict__ vt, unsigned* __restrict__ deg,
    long long* __restrict__ adjp)
{
    __shared__ unsigned short lus[16 * RW];
    int t = threadIdx.x;
    int n0 = blockIdx.x * 16;
    int b = t >> 4, v = t & 15;

    // corner part first: long-latency atomic hides behind transpose streaming
    int e = blockIdx.x * 256 + t;             // 4M threads cover C3 = 1.5M corners
    bool e_ok = (e < C3);
    int f = e / 3;                            // compiler magic-mul
    int c = e - 3 * f;
    int dst = 0, p0 = 0, p1 = 0;
    unsigned rv = 0;
    if (e_ok) {
        int a  = faces[3 * f + 0];            // face row: 3x coalesced-ish, L1-shared
        int bb = faces[3 * f + 1];
        int cc = faces[3 * f + 2];
        dst = (c == 0) ? a : (c == 1) ? bb : cc;
        p0  = (c == 0) ? bb : a;
        p1  = (c == 2) ? bb : cc;
        rv = atomicAdd(&deg[dst], 2u);        // slot allocator
    }

    const float* s = vert + (size_t)b * (N * 3) + (size_t)(n0 + v) * 3;
    lus[v * RW + 0 * 16 + b] = f2bf(s[0]);
    lus[v * RW + 1 * 16 + b] = f2bf(s[1]);
    lus[v * RW + 2 * 16 + b] = f2bf(s[2]);
    __syncthreads();
    const uint2* lu2 = (const uint2*)lus;
    uint2* d2 = (uint2*)(vt + (size_t)n0 * RW);
    if (t < 192) d2[t] = lu2[t];              // coalesced 1536 B per block

    if (e_ok) {
        unsigned pi = rv >> 1;                // pair index within the vertex region
        if (pi < (unsigned)CAP)               // overflow impossible in practice (P~2e-8)
            adjp[(size_t)dst * CAP + pi] =
                (unsigned long long)(unsigned)p0 | ((unsigned long long)(unsigned)p1 << 32);
    }
}

// 4 lanes per vertex; lane q owns batches 4q..4q+3 via uint2 (8 B) loads.
__device__ __forceinline__ void acc_row(const unsigned short* __restrict__ r,
                                        int q, float (&acc)[3][4]) {
#pragma unroll
    for (int cc = 0; cc < 3; ++cc) {
        uint2 u = *(const uint2*)(r + cc * 16 + 4 * q);
        acc[cc][0] += __uint_as_float(u.x << 16);
        acc[cc][1] += __uint_as_float(u.x & 0xFFFF0000u);
        acc[cc][2] += __uint_as_float(u.y << 16);
        acc[cc][3] += __uint_as_float(u.y & 0xFFFF0000u);
    }
}

template <int CAP>
__global__ __launch_bounds__(256) void uls_gather_direct(
    const unsigned short* __restrict__ vt, const int* __restrict__ adj,
    const unsigned* __restrict__ deg, float* __restrict__ out)
{
    __shared__ float lds[16 * 65];
    int t = threadIdx.x;
    int q = t & 3;
    int v = t >> 2;
    int n = blockIdx.x * 64 + v;
    bool n_ok = (n < N);

    unsigned d = n_ok ? deg[n] : 0u;
    if (d > 2u * CAP) d = 2u * CAP;
    const int* a0 = adj + (size_t)n * (CAP * 2);   // region base (ints)

    float acc[3][4] = {{0,0,0,0},{0,0,0,0},{0,0,0,0}};
    unsigned j = 0;
    for (; j + 4 <= d; j += 4) {
        int2 p0 = *(const int2*)(a0 + j);
        int2 p1 = *(const int2*)(a0 + j + 2);
        acc_row(vt + (size_t)p0.x * RW, q, acc);
        acc_row(vt + (size_t)p0.y * RW, q, acc);
        acc_row(vt + (size_t)p1.x * RW, q, acc);
        acc_row(vt + (size_t)p1.y * RW, q, acc);
    }
    if (j < d) {
        int2 p0 = *(const int2*)(a0 + j);
        acc_row(vt + (size_t)p0.x * RW, q, acc);
        acc_row(vt + (size_t)p0.y * RW, q, acc);
    }

    if (n_ok) {
        float self[3][4];
        const unsigned short* rs = vt + (size_t)n * RW;
#pragma unroll
        for (int cc = 0; cc < 3; ++cc) {
            uint2 u = *(const uint2*)(rs + cc * 16 + 4 * q);
            self[cc][0] = __uint_as_float(u.x << 16);
            self[cc][1] = __uint_as_float(u.x & 0xFFFF0000u);
            self[cc][2] = __uint_as_float(u.y << 16);
            self[cc][3] = __uint_as_float(u.y & 0xFFFF0000u);
        }
        float inv = 1.0f / fmaxf((float)d, 1.0f);
#pragma unroll
        for (int k = 0; k < 4; ++k) {
            float lx = acc[0][k] * inv - self[0][k];
            float ly = acc[1][k] * inv - self[1][k];
            float lz = acc[2][k] * inv - self[2][k];
            lds[(4 * q + k) * 65 + v] = sqrtf(lx * lx + ly * ly + lz * lz);
        }
    }
    __syncthreads();
    int vo = t & 63;
    int nn = blockIdx.x * 64 + vo;
    if (nn < N) {
#pragma unroll
        for (int k = 0; k < 4; ++k) {
            int bo = (t >> 6) + 4 * k;
            out[(size_t)bo * N + nn] = lds[bo * 65 + vo];
        }
    }
}

// ================= CSR fallback (R5 structure, no nontemporal) =================

__global__ __launch_bounds__(256) void uls_setup_csr(
    const float* __restrict__ vert, const int* __restrict__ faces,
    unsigned short* __restrict__ vt, unsigned* __restrict__ deg,
    unsigned* __restrict__ rank)
{
    __shared__ unsigned short lus[16 * RW];
    int t = threadIdx.x;
    int n0 = blockIdx.x * 16;
    int b = t >> 4, v = t & 15;
    int e = blockIdx.x * 256 + t;
    unsigned rv = 0;
    bool e_ok = (e < C3);
    int dst = e_ok ? faces[e] : 0;
    if (e_ok) rv = atomicAdd(&deg[dst], 2u);
    const float* s = vert + (size_t)b * (N * 3) + (size_t)(n0 + v) * 3;
    lus[v * RW + 0 * 16 + b] = f2bf(s[0]);
    lus[v * RW + 1 * 16 + b] = f2bf(s[1]);
    lus[v * RW + 2 * 16 + b] = f2bf(s[2]);
    __syncthreads();
    const uint2* lu2 = (const uint2*)lus;
    uint2* d2 = (uint2*)(vt + (size_t)n0 * RW);
    if (t < 192) d2[t] = lu2[t];
    if (e_ok) rank[e] = rv;
}

__global__ __launch_bounds__(256) void uls_alloc(
    const unsigned* __restrict__ deg, unsigned* __restrict__ start,
    unsigned* __restrict__ counter)
{
    __shared__ unsigned s[256];
    __shared__ unsigned base;
    int t = threadIdx.x;
    int n = blockIdx.x * 256 + t;
    unsigned d = (n < N) ? deg[n] : 0u;
    s[t] = d;
    __syncthreads();
    for (int off = 1; off < 256; off <<= 1) {
        unsigned v = (t >= off) ? s[t - off] : 0u;
        __syncthreads();
        s[t] += v;
        __syncthreads();
    }
    if (t == 255) base = atomicAdd(counter, s[255]);
    __syncthreads();
    if (n < N) start[n] = base + (s[t] - d);
}

__global__ __launch_bounds__(256) void uls_fill(
    const int* __restrict__ faces, const unsigned* __restrict__ start,
    const unsigned* __restrict__ rank, int* __restrict__ adj)
{
    int e = blockIdx.x * 256 + threadIdx.x;
    if (e >= C3) return;
    int f = e / 3;
    int c = e - 3 * f;
    int a  = faces[3 * f + 0];
    int b  = faces[3 * f + 1];
    int cc = faces[3 * f + 2];
    int dst = (c == 0) ? a : (c == 1) ? b : cc;
    int p0  = (c == 0) ? b : a;
    int p1  = (c == 2) ? b : cc;
    unsigned p = start[dst] + rank[e];
    *(int2*)(adj + p) = make_int2(p0, p1);
}

__global__ __launch_bounds__(256) void uls_gather_csr(
    const unsigned short* __restrict__ vt, const int* __restrict__ adj,
    const unsigned* __restrict__ start, const unsigned* __restrict__ deg,
    float* __restrict__ out)
{
    __shared__ float lds[16 * 65];
    int t = threadIdx.x;
    int q = t & 3;
    int v = t >> 2;
    int n = blockIdx.x * 64 + v;
    bool n_ok = (n < N);
    unsigned d  = n_ok ? deg[n]   : 0u;
    unsigned s0 = n_ok ? start[n] : 0u;
    float acc[3][4] = {{0,0,0,0},{0,0,0,0},{0,0,0,0}};
    unsigned j = 0;
    for (; j + 4 <= d; j += 4) {
        int2 p0 = *(const int2*)(adj + s0 + j);
        int2 p1 = *(const int2*)(adj + s0 + j + 2);
        acc_row(vt + (size_t)p0.x * RW, q, acc);
        acc_row(vt + (size_t)p0.y * RW, q, acc);
        acc_row(vt + (size_t)p1.x * RW, q, acc);
        acc_row(vt + (size_t)p1.y * RW, q, acc);
    }
    if (j < d) {
        int2 p0 = *(const int2*)(adj + s0 + j);
        acc_row(vt + (size_t)p0.x * RW, q, acc);
        acc_row(vt + (size_t)p0.y * RW, q, acc);
    }
    if (n_ok) {
        float self[3][4];
        const unsigned short* rs = vt + (size_t)n * RW;
#pragma unroll
        for (int cc = 0; cc < 3; ++cc) {
            uint2 u = *(const uint2*)(rs + cc * 16 + 4 * q);
            self[cc][0] = __uint_as_float(u.x << 16);
            self[cc][1] = __uint_as_float(u.x & 0xFFFF0000u);
            self[cc][2] = __uint_as_float(u.y << 16);
            self[cc][3] = __uint_as_float(u.y & 0xFFFF0000u);
        }
        float inv = 1.0f / fmaxf((float)d, 1.0f);
#pragma unroll
        for (int k = 0; k < 4; ++k) {
            float lx = acc[0][k] * inv - self[0][k];
            float ly = acc[1][k] * inv - self[1][k];
            float lz = acc[2][k] * inv - self[2][k];
            lds[(4 * q + k) * 65 + v] = sqrtf(lx * lx + ly * ly + lz * lz);
        }
    }
    __syncthreads();
    int vo = t & 63;
    int nn = blockIdx.x * 64 + vo;
    if (nn < N) {
#pragma unroll
        for (int k = 0; k < 4; ++k) {
            int bo = (t >> 6) + 4 * k;
            out[(size_t)bo * N + nn] = lds[bo * 65 + vo];
        }
    }
}

// ================= launcher =================

template <int CAP>
static void launch_direct(const float* vert, const int* faces, float* out,
                          char* ws, hipStream_t stream) {
    unsigned short* vt  = (unsigned short*)(ws + D_VT);
    unsigned*       deg = (unsigned*)(ws + D_DEG);
    long long*      adj = (long long*)(ws + D_ADJ);
    hipMemsetAsync(deg, 0, (size_t)N * sizeof(unsigned), stream);
    uls_setup_direct<CAP><<<N / 16, 256, 0, stream>>>(vert, faces, vt, deg, adj);
    uls_gather_direct<CAP><<<(N + 63) / 64, 256, 0, stream>>>(vt, (const int*)adj, deg, out);
}

extern "C" void kernel_launch(void* const* d_in, const int* in_sizes, int n_in,
                              void* d_out, int out_size, void* d_ws, size_t ws_size,
                              hipStream_t stream) {
    const float* vert  = (const float*)d_in[0];
    const int*   faces = (const int*)d_in[1];
    float* out = (float*)d_out;
    char* ws = (char*)d_ws;

    if (ws_size >= ws_direct(32)) {
        launch_direct<32>(vert, faces, out, ws, stream);
    } else if (ws_size >= ws_direct(28)) {
        launch_direct<28>(vert, faces, out, ws, stream);
    } else {
        // CSR pipeline (proven at 264.6 us)
        unsigned short* vt      = (unsigned short*)(ws + C_VT);
        int*            adj     = (int*)(ws + C_ADJ);
        unsigned*       deg     = (unsigned*)(ws + C_DEG);
        unsigned*       counter = (unsigned*)(ws + C_CNT);
        unsigned*       start   = (unsigned*)(ws + C_STA);
        unsigned*       rank    = (unsigned*)(ws + C_RNK);
        hipMemsetAsync(ws + C_DEG, 0, (C_CNT + 256) - C_DEG, stream);
        uls_setup_csr<<<N / 16, 256, 0, stream>>>(vert, faces, vt, deg, rank);
        uls_alloc<<<(N + 255) / 256, 256, 0, stream>>>(deg, start, counter);
        uls_fill<<<(C3 + 255) / 256, 256, 0, stream>>>(faces, start, rank, adj);
        uls_gather_csr<<<(N + 63) / 64, 256, 0, stream>>>(vt, adj, start, deg, out);
    }
}

// Round 8
// 263.008 us; speedup vs baseline: 1.1033x; 1.0106x over previous
//
#include <hip/hip_runtime.h>

// Problem constants (fixed by the reference file).
static constexpr int B = 16;
static constexpr int N = 250000;   // 15625 * 16
static constexpr int F = 500000;
static constexpr int C3 = 3 * F;   // corners = 1,500,000
static constexpr int E = 6 * F;    // directed edges (CSR fallback)
static constexpr int RW = 48;      // ushorts per vt row: 3 comps * 16 batches (96 B)
static constexpr int CAP = 24;     // pair capacity/vertex (Poisson(6); P(>=24) ~ 3e-11)
static constexpr int DS  = 16;     // deg padding: 16 uints = one 64 B line per counter

// ---- DIRECT layout (bytes): vt | degp (line-padded) | adjp[N][CAP] ----
static constexpr size_t D_VT  = 0;                                   // 24,000,000
static constexpr size_t D_DEG = (size_t)N * RW * 2;                  // 24,000,000 (+16 MB)
static constexpr size_t D_ADJ = D_DEG + (size_t)N * DS * 4;          // 40,000,000
static constexpr size_t D_NEED = D_ADJ + (size_t)N * CAP * 8;        // 88,000,000 (<= proven 89 MB)

// ---- CSR fallback layout (R5-proven structure) ----
static constexpr size_t C_VT  = 0;
static constexpr size_t C_ADJ = (size_t)N * RW * 2;
static constexpr size_t C_DEG = C_ADJ + (size_t)E * sizeof(int);
static constexpr size_t C_CNT = C_DEG + (size_t)N * sizeof(unsigned);
static constexpr size_t C_STA = C_CNT + 256;
static constexpr size_t C_RNK = C_STA + (size_t)N * sizeof(unsigned);

__device__ __forceinline__ unsigned short f2bf(float f) {
    unsigned u = __float_as_uint(f);
    return (unsigned short)((u + 0x7FFFu + ((u >> 16) & 1u)) >> 16);  // RNE
}

// ================= DIRECT path =================

// Fused: transpose (B,N,3)fp32 -> (N,3,16)bf16  +  corner rank  +  adj write.
// degp has ONE counter per 64 B line: the with-return atomic's line-ownership
// ping-pong depth drops from ~96 ops/line to ~6 (the R3-R7 121 us invariant).
__global__ __launch_bounds__(256) void uls_setup_direct(
    const float* __restrict__ vert, const int* __restrict__ faces,
    unsigned short* __restrict__ vt, unsigned* __restrict__ degp,
    long long* __restrict__ adjp)
{
    __shared__ unsigned short lus[16 * RW];
    int t = threadIdx.x;
    int n0 = blockIdx.x * 16;
    int b = t >> 4, v = t & 15;

    // corner part first: atomic latency hides behind transpose streaming
    int e = blockIdx.x * 256 + t;             // 4M threads cover C3 = 1.5M corners
    bool e_ok = (e < C3);
    int f = e / 3;
    int c = e - 3 * f;
    int dst = 0, p0 = 0, p1 = 0;
    unsigned rv = 0;
    if (e_ok) {
        int a  = faces[3 * f + 0];
        int bb = faces[3 * f + 1];
        int cc = faces[3 * f + 2];
        dst = (c == 0) ? a : (c == 1) ? bb : cc;
        p0  = (c == 0) ? bb : a;
        p1  = (c == 2) ? bb : cc;
        rv = atomicAdd(&degp[(size_t)dst * DS], 2u);   // slot allocator (padded line)
    }

    const float* s = vert + (size_t)b * (N * 3) + (size_t)(n0 + v) * 3;
    lus[v * RW + 0 * 16 + b] = f2bf(s[0]);
    lus[v * RW + 1 * 16 + b] = f2bf(s[1]);
    lus[v * RW + 2 * 16 + b] = f2bf(s[2]);
    __syncthreads();
    const uint2* lu2 = (const uint2*)lus;
    uint2* d2 = (uint2*)(vt + (size_t)n0 * RW);
    if (t < 192) d2[t] = lu2[t];              // coalesced 1536 B per block

    if (e_ok) {
        unsigned pi = rv >> 1;                // pair index within the vertex region
        if (pi < (unsigned)CAP)               // overflow: P ~ 3e-11 per vertex
            adjp[(size_t)dst * CAP + pi] =
                (unsigned long long)(unsigned)p0 | ((unsigned long long)(unsigned)p1 << 32);
    }
}

// 4 lanes per vertex; lane q owns batches 4q..4q+3 via uint2 (8 B) loads.
__device__ __forceinline__ void acc_row(const unsigned short* __restrict__ r,
                                        int q, float (&acc)[3][4]) {
#pragma unroll
    for (int cc = 0; cc < 3; ++cc) {
        uint2 u = *(const uint2*)(r + cc * 16 + 4 * q);
        acc[cc][0] += __uint_as_float(u.x << 16);
        acc[cc][1] += __uint_as_float(u.x & 0xFFFF0000u);
        acc[cc][2] += __uint_as_float(u.y << 16);
        acc[cc][3] += __uint_as_float(u.y & 0xFFFF0000u);
    }
}

__global__ __launch_bounds__(256) void uls_gather_direct(
    const unsigned short* __restrict__ vt, const int* __restrict__ adj,
    const unsigned* __restrict__ degp, float* __restrict__ out)
{
    __shared__ float lds[16 * 65];
    int t = threadIdx.x;
    int q = t & 3;
    int v = t >> 2;
    int n = blockIdx.x * 64 + v;
    bool n_ok = (n < N);

    unsigned d = n_ok ? degp[(size_t)n * DS] : 0u;
    if (d > 2u * CAP) d = 2u * CAP;
    const int* a0 = adj + (size_t)n * (CAP * 2);   // region base (ints)

    float acc[3][4] = {{0,0,0,0},{0,0,0,0},{0,0,0,0}};
    unsigned j = 0;
    for (; j + 4 <= d; j += 4) {
        int2 p0 = *(const int2*)(a0 + j);
        int2 p1 = *(const int2*)(a0 + j + 2);
        acc_row(vt + (size_t)p0.x * RW, q, acc);
        acc_row(vt + (size_t)p0.y * RW, q, acc);
        acc_row(vt + (size_t)p1.x * RW, q, acc);
        acc_row(vt + (size_t)p1.y * RW, q, acc);
    }
    if (j < d) {
        int2 p0 = *(const int2*)(a0 + j);
        acc_row(vt + (size_t)p0.x * RW, q, acc);
        acc_row(vt + (size_t)p0.y * RW, q, acc);
    }

    if (n_ok) {
        float self[3][4];
        const unsigned short* rs = vt + (size_t)n * RW;
#pragma unroll
        for (int cc = 0; cc < 3; ++cc) {
            uint2 u = *(const uint2*)(rs + cc * 16 + 4 * q);
            self[cc][0] = __uint_as_float(u.x << 16);
            self[cc][1] = __uint_as_float(u.x & 0xFFFF0000u);
            self[cc][2] = __uint_as_float(u.y << 16);
            self[cc][3] = __uint_as_float(u.y & 0xFFFF0000u);
        }
        float inv = 1.0f / fmaxf((float)d, 1.0f);
#pragma unroll
        for (int k = 0; k < 4; ++k) {
            float lx = acc[0][k] * inv - self[0][k];
            float ly = acc[1][k] * inv - self[1][k];
            float lz = acc[2][k] * inv - self[2][k];
            lds[(4 * q + k) * 65 + v] = sqrtf(lx * lx + ly * ly + lz * lz);
        }
    }
    __syncthreads();
    int vo = t & 63;
    int nn = blockIdx.x * 64 + vo;
    if (nn < N) {
#pragma unroll
        for (int k = 0; k < 4; ++k) {
            int bo = (t >> 6) + 4 * k;
            out[(size_t)bo * N + nn] = lds[bo * 65 + vo];
        }
    }
}

// ================= CSR fallback (R5 structure; used only if ws < 88 MB) =================

__global__ __launch_bounds__(256) void uls_setup_csr(
    const float* __restrict__ vert, const int* __restrict__ faces,
    unsigned short* __restrict__ vt, unsigned* __restrict__ deg,
    unsigned* __restrict__ rank)
{
    __shared__ unsigned short lus[16 * RW];
    int t = threadIdx.x;
    int n0 = blockIdx.x * 16;
    int b = t >> 4, v = t & 15;
    int e = blockIdx.x * 256 + t;
    unsigned rv = 0;
    bool e_ok = (e < C3);
    int dst = e_ok ? faces[e] : 0;
    if (e_ok) rv = atomicAdd(&deg[dst], 2u);
    const float* s = vert + (size_t)b * (N * 3) + (size_t)(n0 + v) * 3;
    lus[v * RW + 0 * 16 + b] = f2bf(s[0]);
    lus[v * RW + 1 * 16 + b] = f2bf(s[1]);
    lus[v * RW + 2 * 16 + b] = f2bf(s[2]);
    __syncthreads();
    const uint2* lu2 = (const uint2*)lus;
    uint2* d2 = (uint2*)(vt + (size_t)n0 * RW);
    if (t < 192) d2[t] = lu2[t];
    if (e_ok) rank[e] = rv;
}

__global__ __launch_bounds__(256) void uls_alloc(
    const unsigned* __restrict__ deg, unsigned* __restrict__ start,
    unsigned* __restrict__ counter)
{
    __shared__ unsigned s[256];
    __shared__ unsigned base;
    int t = threadIdx.x;
    int n = blockIdx.x * 256 + t;
    unsigned d = (n < N) ? deg[n] : 0u;
    s[t] = d;
    __syncthreads();
    for (int off = 1; off < 256; off <<= 1) {
        unsigned v = (t >= off) ? s[t - off] : 0u;
        __syncthreads();
        s[t] += v;
        __syncthreads();
    }
    if (t == 255) base = atomicAdd(counter, s[255]);
    __syncthreads();
    if (n < N) start[n] = base + (s[t] - d);
}

__global__ __launch_bounds__(256) void uls_fill(
    const int* __restrict__ faces, const unsigned* __restrict__ start,
    const unsigned* __restrict__ rank, int* __restrict__ adj)
{
    int e = blockIdx.x * 256 + threadIdx.x;
    if (e >= C3) return;
    int f = e / 3;
    int c = e - 3 * f;
    int a  = faces[3 * f + 0];
    int b  = faces[3 * f + 1];
    int cc = faces[3 * f + 2];
    int dst = (c == 0) ? a : (c == 1) ? b : cc;
    int p0  = (c == 0) ? b : a;
    int p1  = (c == 2) ? b : cc;
    unsigned p = start[dst] + rank[e];
    *(int2*)(adj + p) = make_int2(p0, p1);
}

__global__ __launch_bounds__(256) void uls_gather_csr(
    const unsigned short* __restrict__ vt, const int* __restrict__ adj,
    const unsigned* __restrict__ start, const unsigned* __restrict__ deg,
    float* __restrict__ out)
{
    __shared__ float lds[16 * 65];
    int t = threadIdx.x;
    int q = t & 3;
    int v = t >> 2;
    int n = blockIdx.x * 64 + v;
    bool n_ok = (n < N);
    unsigned d  = n_ok ? deg[n]   : 0u;
    unsigned s0 = n_ok ? start[n] : 0u;
    float acc[3][4] = {{0,0,0,0},{0,0,0,0},{0,0,0,0}};
    unsigned j = 0;
    for (; j + 4 <= d; j += 4) {
        int2 p0 = *(const int2*)(adj + s0 + j);
        int2 p1 = *(const int2*)(adj + s0 + j + 2);
        acc_row(vt + (size_t)p0.x * RW, q, acc);
        acc_row(vt + (size_t)p0.y * RW, q, acc);
        acc_row(vt + (size_t)p1.x * RW, q, acc);
        acc_row(vt + (size_t)p1.y * RW, q, acc);
    }
    if (j < d) {
        int2 p0 = *(const int2*)(adj + s0 + j);
        acc_row(vt + (size_t)p0.x * RW, q, acc);
        acc_row(vt + (size_t)p0.y * RW, q, acc);
    }
    if (n_ok) {
        float self[3][4];
        const unsigned short* rs = vt + (size_t)n * RW;
#pragma unroll
        for (int cc = 0; cc < 3; ++cc) {
            uint2 u = *(const uint2*)(rs + cc * 16 + 4 * q);
            self[cc][0] = __uint_as_float(u.x << 16);
            self[cc][1] = __uint_as_float(u.x & 0xFFFF0000u);
            self[cc][2] = __uint_as_float(u.y << 16);
            self[cc][3] = __uint_as_float(u.y & 0xFFFF0000u);
        }
        float inv = 1.0f / fmaxf((float)d, 1.0f);
#pragma unroll
        for (int k = 0; k < 4; ++k) {
            float lx = acc[0][k] * inv - self[0][k];
            float ly = acc[1][k] * inv - self[1][k];
            float lz = acc[2][k] * inv - self[2][k];
            lds[(4 * q + k) * 65 + v] = sqrtf(lx * lx + ly * ly + lz * lz);
        }
    }
    __syncthreads();
    int vo = t & 63;
    int nn = blockIdx.x * 64 + vo;
    if (nn < N) {
#pragma unroll
        for (int k = 0; k < 4; ++k) {
            int bo = (t >> 6) + 4 * k;
            out[(size_t)bo * N + nn] = lds[bo * 65 + vo];
        }
    }
}

// ================= launcher =================

extern "C" void kernel_launch(void* const* d_in, const int* in_sizes, int n_in,
                              void* d_out, int out_size, void* d_ws, size_t ws_size,
                              hipStream_t stream) {
    const float* vert  = (const float*)d_in[0];
    const int*   faces = (const int*)d_in[1];
    float* out = (float*)d_out;
    char* ws = (char*)d_ws;

    if (ws_size >= D_NEED) {
        unsigned short* vt   = (unsigned short*)(ws + D_VT);
        unsigned*       degp = (unsigned*)(ws + D_DEG);
        long long*      adj  = (long long*)(ws + D_ADJ);
        hipMemsetAsync(degp, 0, (size_t)N * DS * 4, stream);
        uls_setup_direct<<<N / 16, 256, 0, stream>>>(vert, faces, vt, degp, adj);
        uls_gather_direct<<<(N + 63) / 64, 256, 0, stream>>>(vt, (const int*)adj, degp, out);
    } else {
        // CSR pipeline (proven at 264.6 us)
        unsigned short* vt      = (unsigned short*)(ws + C_VT);
        int*            adj     = (int*)(ws + C_ADJ);
        unsigned*       deg     = (unsigned*)(ws + C_DEG);
        unsigned*       counter = (unsigned*)(ws + C_CNT);
        unsigned*       start   = (unsigned*)(ws + C_STA);
        unsigned*       rank    = (unsigned*)(ws + C_RNK);
        hipMemsetAsync(ws + C_DEG, 0, (C_CNT + 256) - C_DEG, stream);
        uls_setup_csr<<<N / 16, 256, 0, stream>>>(vert, faces, vt, deg, rank);
        uls_alloc<<<(N + 255) / 256, 256, 0, stream>>>(deg, start, counter);
        uls_fill<<<(C3 + 255) / 256, 256, 0, stream>>>(faces, start, rank, adj);
        uls_gather_csr<<<(N + 63) / 64, 256, 0, stream>>>(vt, adj, start, deg, out);
    }
}